// Round 3
// baseline (5624.886 us; speedup 1.0000x reference)
//
#include <hip/hip_runtime.h>
#include <cstdint>

#define S 64
#define SSZ (S*S)        // 4096  (one z-plane)
#define SV  (S*S*S)      // 262144 (one channel volume)
#define CH 64
#define NB 2

// Module-resident zero word: halo lanes of the global->LDS DMA read this.
__device__ float g_zero = 0.0f;

// ---------------------------------------------------------------------------
// Kernel 1: depthwise 5x5x5 conv, pad 2, + bias -> att1
// CHANGE vs v3: weights staged to LDS once per block (layout [ky][kz*5+kx],
// phase stride 28 dw) and read per ky-phase as 7 uniform ds_read_b128
// broadcasts -> no per-iteration SMEM weight reloads mixing into lgkmcnt.
// Geometry / staging / FP accumulation order unchanged.
// ---------------------------------------------------------------------------
__global__ __launch_bounds__(256, 3) void conv5_dw(const float* __restrict__ x,
                                                   const float* __restrict__ w,   // [64][5][5][5]
                                                   const float* __restrict__ bias,
                                                   float* __restrict__ out) {
    const int ytile = blockIdx.x;           // 0..3
    const int zh    = blockIdx.y;           // 0..1
    const int bc    = blockIdx.z;           // 0..127
    const int c     = bc & (CH - 1);
    const int tid   = threadIdx.x;
    const int tx    = tid & 15;             // x = tx*4 + j
    const int ty    = tid >> 4;             // 0..15
    const int y0    = ytile * 16;
    const int zlo   = zh * 32, zhi = zlo + 32;
    const int zp0   = (zlo - 2 < 0) ? 0 : zlo - 2;
    const int zp1   = (zhi + 1 > S - 1) ? S - 1 : zhi + 1;

    const float* __restrict__ xin = x + (size_t)bc * SV;
    float* __restrict__ o         = out + (size_t)bc * SV;
    const float* __restrict__ wc  = w + c * 125;
    const float bv = bias[c];

    __shared__ float buf[2][20 * 69];       // rows gy = y0-2..y0+17, cols gx = -2..65, stride 69
    __shared__ __align__(16) float wlds[5 * 28 + 4];   // [ky][kz*5+kx], pad 28/phase

    // weights -> LDS (transposed to ky-major)
    for (int idx = tid; idx < 125; idx += 256) {
        int kz  = idx / 25;
        int rem = idx - kz * 25;
        int ky  = rem / 5;
        int kx  = rem - ky * 5;
        wlds[ky * 28 + kz * 5 + kx] = wc[idx];
    }

    int lofs[6], gofs[6];
    unsigned vmask = 0;
#pragma unroll
    for (int k = 0; k < 6; ++k) {
        int idx = tid + k * 256;
        lofs[k] = -1; gofs[k] = 0;
        if (idx < 1360) {
            int r = idx / 68, col = idx - r * 68;
            lofs[k] = r * 69 + col;
            int gy = y0 - 2 + r, gx = col - 2;
            if (gy >= 0 && gy < S && gx >= 0 && gx < S) {
                gofs[k] = gy * S + gx;
                vmask |= 1u << k;
            }
        }
    }

    float acc[5][4];
#pragma unroll
    for (int s5 = 0; s5 < 5; ++s5)
#pragma unroll
        for (int j = 0; j < 4; ++j) acc[s5][j] = 0.f;

    float v[6];
#pragma unroll
    for (int k = 0; k < 6; ++k) {
        float t = xin[zp0 * SSZ + gofs[k]];
        v[k] = ((vmask >> k) & 1) ? t : 0.f;
    }
#pragma unroll
    for (int k = 0; k < 6; ++k) if (lofs[k] >= 0) buf[0][lofs[k]] = v[k];
    __syncthreads();

    int ibuf = 0;
    for (int zp = zp0; zp <= zp1; ++zp) {
        const float* __restrict__ cur = buf[ibuf];
        const int  znx  = zp + 1;
        const bool more = (znx <= zp1);
        if (more) {
#pragma unroll
            for (int k = 0; k < 6; ++k) {
                float t = xin[znx * SSZ + gofs[k]];
                v[k] = ((vmask >> k) & 1) ? t : 0.f;
            }
        }
#pragma unroll
        for (int ky = 0; ky < 5; ++ky) {
            const float* rowp = &cur[(ty + ky) * 69 + tx * 4];
            float rr[8];
#pragma unroll
            for (int q = 0; q < 8; ++q) rr[q] = rowp[q];
            // 7 uniform b128 broadcasts: 28 dwords (25 weights + 3 slack)
            const float4* wp = (const float4*)&wlds[ky * 28];
            float wf[28];
#pragma unroll
            for (int t = 0; t < 7; ++t) {
                float4 q4 = wp[t];
                wf[4*t] = q4.x; wf[4*t+1] = q4.y; wf[4*t+2] = q4.z; wf[4*t+3] = q4.w;
            }
#pragma unroll
            for (int s5 = 0; s5 < 5; ++s5) {
#pragma unroll
                for (int kx = 0; kx < 5; ++kx) {
                    const float wv = wf[(4 - s5) * 5 + kx];
                    acc[s5][0] = fmaf(wv, rr[kx + 0], acc[s5][0]);
                    acc[s5][1] = fmaf(wv, rr[kx + 1], acc[s5][1]);
                    acc[s5][2] = fmaf(wv, rr[kx + 2], acc[s5][2]);
                    acc[s5][3] = fmaf(wv, rr[kx + 3], acc[s5][3]);
                }
            }
        }
        if (more) {
#pragma unroll
            for (int k = 0; k < 6; ++k) if (lofs[k] >= 0) buf[ibuf ^ 1][lofs[k]] = v[k];
        }
        int p = zp - 2;
        if (p >= zlo && p < zhi) {
            float* orow = o + p * SSZ + (y0 + ty) * S + tx * 4;
#pragma unroll
            for (int j = 0; j < 4; ++j) orow[j] = acc[0][j] + bv;
        }
#pragma unroll
        for (int s5 = 0; s5 < 4; ++s5)
#pragma unroll
            for (int j = 0; j < 4; ++j) acc[s5][j] = acc[s5 + 1][j];
#pragma unroll
        for (int j = 0; j < 4; ++j) acc[4][j] = 0.f;
        __syncthreads();
        ibuf ^= 1;
    }
#pragma unroll
    for (int s5 = 0; s5 < 4; ++s5) {
        int p = zp1 - 1 + s5;
        if (p >= zlo && p < zhi) {
            float* orow = o + p * SSZ + (y0 + ty) * S + tx * 4;
#pragma unroll
            for (int j = 0; j < 4; ++j) orow[j] = acc[s5][j] + bv;
        }
    }
}

// ---------------------------------------------------------------------------
// Kernel 2 (v4): depthwise 7x7x7 conv, dilation 3, pad 9, + bias -> att2
//
// CHANGES vs v3:
//  * Weights in LDS (staged once, layout [ky][kz][8]); the inner loop reads
//    them as uniform-address ds_read_b128 broadcasts (conflict-free, DS is
//    in-order -> fine-grained lgkmcnt, no SMEM drains, no scratch spills).
//  * 8 x-outputs per thread (reuse 8 FMA per weight): 9 x-threads
//    (rx in 0..2, ig in 0..2), window = 14 slots = 3x b128 + 1x b64,
//    base dword 8*ig (32B-aligned).
//  * 288 threads = 9 x * 32 y, 2 exact y-tiles (zero y-waste).
//  * Row stride 132 dw (quad-bank stride 33, odd -> row reads spread
//    across all 8 bank-quads), residue substride 44.
//  * __launch_bounds__(288,3): VGPR<=170 -> 2 blocks/CU (LDS 54.5KB each).
// ---------------------------------------------------------------------------
#define RS7   132          // LDS row stride (dwords) = 3*44
#define RXS7  44           // rx substride (dwords), 30 used + 14 pad
#define NROW7 50           // rows gy = y0-9 .. y0+40   (32 out rows + 18 halo)
#define NCH7  23           // staging chunks of 288 dwords
#define LPP7  (NCH7*288)   // 6624 >= 50*132 = 6600

__global__ __launch_bounds__(288, 3) void conv7_dil(const float* __restrict__ in,
                                                    const float* __restrict__ w,   // [64][7][7][7]
                                                    const float* __restrict__ bias,
                                                    float* __restrict__ out) {
    const int ytile = blockIdx.x;        // 0..1  (32-row tiles, exact)
    const int rz    = blockIdx.y;        // 0..2  (input z residue)
    const int bc    = blockIdx.z;        // 0..127
    const int c     = bc & (CH - 1);
    const int tid   = threadIdx.x;
    const int xcol  = tid % 9;
    const int ty    = tid / 9;           // 0..31
    const int rx    = xcol % 3;
    const int ig    = xcol / 3;          // 0..2
    const int y0    = ytile * 32;

    const float* __restrict__ xin = in + (size_t)bc * SV;
    float* __restrict__ o         = out + (size_t)bc * SV;
    const float* __restrict__ wc  = w + c * 343;
    const float bv = bias[c];

    __shared__ __align__(16) float buf[2][LPP7];        // 2*26496 B
    __shared__ __align__(16) float wlds[7 * 56];        // [ky][kz][8] = 392 dw

    // ---- weights -> LDS, transposed to [ky][kz][kx] with kz-stride 8 ----
    for (int idx = tid; idx < 343; idx += 288) {
        int kz  = idx / 49;
        int rem = idx - kz * 49;
        int ky  = rem / 7;
        int kx  = rem - ky * 7;
        wlds[ky * 56 + kz * 8 + kx] = wc[idx];
    }

    // ---- staging offsets: linear LDS idx -> (r, rxs, ts) -> global byte ofs ----
    int gofs[NCH7];
#pragma unroll
    for (int k = 0; k < NCH7; ++k) {
        int idx = tid + k * 288;
        int r   = idx / RS7;
        int rem = idx - r * RS7;
        int rxs = rem / RXS7;
        int ts  = rem - rxs * RXS7;
        int gy  = y0 - 9 + r;
        int gx  = 3 * ts + rxs - 9;
        gofs[k] = (r < NROW7 && ts < 30 && gy >= 0 && gy < S && gx >= 0 && gx < S)
                  ? (gy * S + gx) * 4 : -1;
    }

    const int zi0     = rz;
    const int zi_last = (S - 1) - ((S - 1 - rz) % 3);

    // ring accumulators: slot s holds output p = zi - 9 + 3s (weight kz = 6-s)
    float acc[7][8];
#pragma unroll
    for (int s = 0; s < 7; ++s)
#pragma unroll
        for (int j = 0; j < 8; ++j) acc[s][j] = 0.f;

    // prologue: stage plane zi0 into buf[0]
    {
        const char* pb = (const char*)(xin + (size_t)zi0 * SSZ);
#pragma unroll
        for (int k = 0; k < NCH7; ++k) {
            const float* gp = (gofs[k] >= 0) ? (const float*)(pb + gofs[k]) : &g_zero;
            __builtin_amdgcn_global_load_lds(
                (const __attribute__((address_space(1))) void*)gp,
                (__attribute__((address_space(3))) void*)&buf[0][tid + k * 288],
                4, 0, 0);
        }
    }
    __syncthreads();

    const int rbase = rx * RXS7 + 8 * ig;
    int ib = 0;
#pragma unroll 1
    for (int zi = zi0; zi <= zi_last; zi += 3) {
        // issue DMA for next plane into buf[ib^1]; drained at the barrier below
        if (zi < zi_last) {
            const char* pb = (const char*)(xin + (size_t)(zi + 3) * SSZ);
#pragma unroll
            for (int k = 0; k < NCH7; ++k) {
                const float* gp = (gofs[k] >= 0) ? (const float*)(pb + gofs[k]) : &g_zero;
                __builtin_amdgcn_global_load_lds(
                    (const __attribute__((address_space(1))) void*)gp,
                    (__attribute__((address_space(3))) void*)&buf[ib ^ 1][tid + k * 288],
                    4, 0, 0);
            }
        }

        const float* __restrict__ cur = buf[ib];
#pragma unroll
        for (int ky = 0; ky < 7; ++ky) {
            const float* rp = cur + (ty + 3 * ky) * RS7 + rbase;
            float4 A  = *(const float4*)rp;          // slots 8ig+0..3
            float4 B  = *(const float4*)(rp + 4);    // slots 8ig+4..7
            float4 Cq = *(const float4*)(rp + 8);    // slots 8ig+8..11
            float2 D  = *(const float2*)(rp + 12);   // slots 8ig+12..13
            float rr[14] = {A.x, A.y, A.z, A.w, B.x, B.y, B.z, B.w,
                            Cq.x, Cq.y, Cq.z, Cq.w, D.x, D.y};
#pragma unroll
            for (int s = 0; s < 7; ++s) {
                // uniform-address broadcast of 7 weights (kz = 6-s, row ky)
                const float4* wq = (const float4*)&wlds[ky * 56 + (6 - s) * 8];
                float4 qa = wq[0], qb = wq[1];
                float wf[7] = {qa.x, qa.y, qa.z, qa.w, qb.x, qb.y, qb.z};
#pragma unroll
                for (int kx = 0; kx < 7; ++kx) {
                    const float wv = wf[kx];
#pragma unroll
                    for (int j = 0; j < 8; ++j)
                        acc[s][j] = fmaf(wv, rr[kx + j], acc[s][j]);
                }
            }
        }

        // emit slot 0: output plane p = zi - 9
        const int p = zi - 9;
        if (p >= 0) {
            float* ob = o + p * SSZ + (y0 + ty) * S;
#pragma unroll
            for (int j = 0; j < 8; ++j) {
                const int xx = rx + 24 * ig + 3 * j;
                if (xx < S) ob[xx] = acc[0][j] + bv;
            }
        }
        // shift ring
#pragma unroll
        for (int s = 0; s < 6; ++s)
#pragma unroll
            for (int j = 0; j < 8; ++j) acc[s][j] = acc[s + 1][j];
#pragma unroll
        for (int j = 0; j < 8; ++j) acc[6][j] = 0.f;

        __syncthreads();   // drains DMA: buf[ib^1] complete for next iter
        ib ^= 1;
    }

    // flush: slot s holds p = zi_last - 6 + 3s  (s = 0..5)
#pragma unroll
    for (int s = 0; s < 6; ++s) {
        const int p = zi_last - 6 + 3 * s;
        if (p < S) {
            float* ob = o + p * SSZ + (y0 + ty) * S;
#pragma unroll
            for (int j = 0; j < 8; ++j) {
                const int xx = rx + 24 * ig + 3 * j;
                if (xx < S) ob[xx] = acc[s][j] + bv;
            }
        }
    }
}

// ---------------------------------------------------------------------------
// Kernel 3: channel mean & max over the 128 channels of [att1; att2]
// ---------------------------------------------------------------------------
__global__ __launch_bounds__(256) void reduce_ch(const float* __restrict__ att1,
                                                 const float* __restrict__ att2,
                                                 float* __restrict__ pooled) {
    const int idx = blockIdx.x * 256 + threadIdx.x;    // over NB*SV/4
    const int e   = idx * 4;
    const int b   = e >> 18;                           // SV = 2^18
    const int s   = e & (SV - 1);
    const float4* a1 = (const float4*)(att1 + (size_t)b * CH * SV + s);
    const float4* a2 = (const float4*)(att2 + (size_t)b * CH * SV + s);
    const int stride = SV / 4;

    float4 sum = make_float4(0.f, 0.f, 0.f, 0.f);
    float4 mx  = make_float4(-3.4e38f, -3.4e38f, -3.4e38f, -3.4e38f);
#pragma unroll 8
    for (int c = 0; c < CH; ++c) {
        float4 v1 = a1[c * stride];
        float4 v2 = a2[c * stride];
        sum.x += v1.x + v2.x; sum.y += v1.y + v2.y;
        sum.z += v1.z + v2.z; sum.w += v1.w + v2.w;
        mx.x = fmaxf(mx.x, fmaxf(v1.x, v2.x)); mx.y = fmaxf(mx.y, fmaxf(v1.y, v2.y));
        mx.z = fmaxf(mx.z, fmaxf(v1.z, v2.z)); mx.w = fmaxf(mx.w, fmaxf(v1.w, v2.w));
    }
    const float inv = 1.f / 128.f;
    sum.x *= inv; sum.y *= inv; sum.z *= inv; sum.w *= inv;
    *(float4*)(pooled + (size_t)b * 2 * SV + s)      = sum;
    *(float4*)(pooled + (size_t)b * 2 * SV + SV + s) = mx;
}

// ---------------------------------------------------------------------------
// Kernel 4: gate = sigmoid(conv3d(pooled, ws, pad 3) + bs)   [B][2][64^3]
// ---------------------------------------------------------------------------
__global__ __launch_bounds__(256) void gate_conv(const float* __restrict__ pooled,
                                                 const float* __restrict__ wsg,  // [2][2][7][7][7]
                                                 const float* __restrict__ bs,
                                                 float* __restrict__ gate) {
    const int zc  = blockIdx.x;             // 0..63
    const int yt  = blockIdx.y;             // 0..7
    const int b   = blockIdx.z;             // 0..1
    const int tid = threadIdx.x;
    const int tx  = tid & 15;
    const int ty  = (tid >> 4) & 7;
    const int oc  = tid >> 7;
    const int y0  = yt * 8;

    __shared__ float sm[2][7][14][72];

    const float* __restrict__ pb = pooled + (size_t)b * 2 * SV;
    for (int idx = tid; idx < 2 * 7 * 14 * 70; idx += 256) {
        int ic   = idx / (7 * 14 * 70);
        int rem  = idx - ic * (7 * 14 * 70);
        int kz   = rem / (14 * 70);
        int rem2 = rem - kz * (14 * 70);
        int r    = rem2 / 70;
        int col  = rem2 - r * 70;
        int gz = zc + kz - 3, gy = y0 + r - 3, gx = col - 3;
        float v = 0.f;
        if (gz >= 0 && gz < S && gy >= 0 && gy < S && gx >= 0 && gx < S)
            v = pb[ic * SV + gz * SSZ + gy * S + gx];
        sm[ic][kz][r][col] = v;
    }
    __syncthreads();

    float acc[4] = {0.f, 0.f, 0.f, 0.f};
    const float* __restrict__ wo = wsg + oc * 686;
    for (int ic = 0; ic < 2; ++ic)
        for (int kz = 0; kz < 7; ++kz) {
#pragma unroll
            for (int ky = 0; ky < 7; ++ky) {
                const float* row = &sm[ic][kz][ty + ky][tx * 4];
                float rr[10];
#pragma unroll
                for (int q = 0; q < 10; ++q) rr[q] = row[q];
                const float* wr = wo + ic * 343 + kz * 49 + ky * 7;
#pragma unroll
                for (int kx = 0; kx < 7; ++kx) {
                    float wvv = wr[kx];
                    acc[0] = fmaf(wvv, rr[kx + 0], acc[0]);
                    acc[1] = fmaf(wvv, rr[kx + 1], acc[1]);
                    acc[2] = fmaf(wvv, rr[kx + 2], acc[2]);
                    acc[3] = fmaf(wvv, rr[kx + 3], acc[3]);
                }
            }
        }
    const float bvv = bs[oc];
    float* g = gate + ((size_t)b * 2 + oc) * SV + zc * SSZ + (y0 + ty) * S + tx * 4;
#pragma unroll
    for (int j = 0; j < 4; ++j)
        g[j] = 1.f / (1.f + __expf(-(acc[j] + bvv)));
}

// ---------------------------------------------------------------------------
// Kernel 5: out = att1*gate0 + att2*gate1 + x
// ---------------------------------------------------------------------------
__global__ __launch_bounds__(256) void combine(const float* __restrict__ att1,
                                               const float* __restrict__ att2,
                                               const float* __restrict__ x,
                                               const float* __restrict__ gate,
                                               float* __restrict__ out) {
    const int idx = blockIdx.x * 256 + threadIdx.x;    // over NB*CH*SV/4
    const int e   = idx * 4;
    const int b   = e >> 24;                           // CH*SV = 2^24
    const int s   = e & (SV - 1);
    float4 a1 = *(const float4*)(att1 + e);
    float4 a2 = *(const float4*)(att2 + e);
    float4 xv = *(const float4*)(x + e);
    float4 g0 = *(const float4*)(gate + (size_t)b * 2 * SV + s);
    float4 g1 = *(const float4*)(gate + (size_t)b * 2 * SV + SV + s);
    float4 r;
    r.x = a1.x * g0.x + a2.x * g1.x + xv.x;
    r.y = a1.y * g0.y + a2.y * g1.y + xv.y;
    r.z = a1.z * g0.z + a2.z * g1.z + xv.z;
    r.w = a1.w * g0.w + a2.w * g1.w + xv.w;
    *(float4*)(out + e) = r;
}

// ---------------------------------------------------------------------------
extern "C" void kernel_launch(void* const* d_in, const int* in_sizes, int n_in,
                              void* d_out, int out_size, void* d_ws, size_t ws_size,
                              hipStream_t stream) {
    const float* x   = (const float*)d_in[0];
    const float* w1  = (const float*)d_in[1];
    const float* b1  = (const float*)d_in[2];
    const float* w2  = (const float*)d_in[3];
    const float* b2  = (const float*)d_in[4];
    const float* wsg = (const float*)d_in[5];
    const float* bs  = (const float*)d_in[6];
    float* out = (float*)d_out;

    float* att1   = (float*)d_ws;                         // 2*64*SV floats
    float* att2   = att1 + (size_t)NB * CH * SV;          // 2*64*SV floats
    float* pooled = att2 + (size_t)NB * CH * SV;          // 2*2*SV floats
    float* gate   = pooled + (size_t)NB * 2 * SV;         // 2*2*SV floats

    conv5_dw <<<dim3(4, 2, NB * CH), 256, 0, stream>>>(x, w1, b1, att1);
    conv7_dil<<<dim3(2, 3, NB * CH), 288, 0, stream>>>(att1, w2, b2, att2);
    reduce_ch<<<(NB * SV / 4) / 256, 256, 0, stream>>>(att1, att2, pooled);
    gate_conv<<<dim3(S, 8, NB), 256, 0, stream>>>(pooled, wsg, bs, gate);
    combine  <<<(NB * CH * SV / 4) / 256, 256, 0, stream>>>(att1, att2, x, gate, out);
}

// Round 4
// 1668.902 us; speedup vs baseline: 3.3704x; 3.3704x over previous
//
#include <hip/hip_runtime.h>
#include <cstdint>

#define S 64
#define SSZ (S*S)        // 4096  (one z-plane)
#define SV  (S*S*S)      // 262144 (one channel volume)
#define CH 64
#define NB 2

// Module-resident zero word: halo lanes of the global->LDS DMA read this.
__device__ float g_zero = 0.0f;

// ---------------------------------------------------------------------------
// Kernel 1: depthwise 5x5x5 conv, pad 2, + bias -> att1
// (reverted to the round-0/round-2 version — no weight-LDS experiment)
// ---------------------------------------------------------------------------
__global__ __launch_bounds__(256) void conv5_dw(const float* __restrict__ x,
                                                const float* __restrict__ w,   // [64][5][5][5]
                                                const float* __restrict__ bias,
                                                float* __restrict__ out) {
    const int ytile = blockIdx.x;           // 0..3
    const int zh    = blockIdx.y;           // 0..1
    const int bc    = blockIdx.z;           // 0..127
    const int c     = bc & (CH - 1);
    const int tid   = threadIdx.x;
    const int tx    = tid & 15;             // x = tx*4 + j
    const int ty    = tid >> 4;             // 0..15
    const int y0    = ytile * 16;
    const int zlo   = zh * 32, zhi = zlo + 32;
    const int zp0   = (zlo - 2 < 0) ? 0 : zlo - 2;
    const int zp1   = (zhi + 1 > S - 1) ? S - 1 : zhi + 1;

    const float* __restrict__ xin = x + (size_t)bc * SV;
    float* __restrict__ o         = out + (size_t)bc * SV;
    const float* __restrict__ wc  = w + c * 125;
    const float bv = bias[c];

    __shared__ float buf[2][20 * 69];       // rows gy = y0-2..y0+17, cols gx = -2..65, stride 69

    int lofs[6], gofs[6];
    unsigned vmask = 0;
#pragma unroll
    for (int k = 0; k < 6; ++k) {
        int idx = tid + k * 256;
        lofs[k] = -1; gofs[k] = 0;
        if (idx < 1360) {
            int r = idx / 68, col = idx - r * 68;
            lofs[k] = r * 69 + col;
            int gy = y0 - 2 + r, gx = col - 2;
            if (gy >= 0 && gy < S && gx >= 0 && gx < S) {
                gofs[k] = gy * S + gx;
                vmask |= 1u << k;
            }
        }
    }

    float acc[5][4];
#pragma unroll
    for (int s5 = 0; s5 < 5; ++s5)
#pragma unroll
        for (int j = 0; j < 4; ++j) acc[s5][j] = 0.f;

    float v[6];
#pragma unroll
    for (int k = 0; k < 6; ++k) {
        float t = xin[zp0 * SSZ + gofs[k]];
        v[k] = ((vmask >> k) & 1) ? t : 0.f;
    }
#pragma unroll
    for (int k = 0; k < 6; ++k) if (lofs[k] >= 0) buf[0][lofs[k]] = v[k];
    __syncthreads();

    int ibuf = 0;
    for (int zp = zp0; zp <= zp1; ++zp) {
        const float* __restrict__ cur = buf[ibuf];
        const int  znx  = zp + 1;
        const bool more = (znx <= zp1);
        if (more) {
#pragma unroll
            for (int k = 0; k < 6; ++k) {
                float t = xin[znx * SSZ + gofs[k]];
                v[k] = ((vmask >> k) & 1) ? t : 0.f;
            }
        }
#pragma unroll
        for (int ky = 0; ky < 5; ++ky) {
            const float* rowp = &cur[(ty + ky) * 69 + tx * 4];
            float rr[8];
#pragma unroll
            for (int q = 0; q < 8; ++q) rr[q] = rowp[q];
#pragma unroll
            for (int s5 = 0; s5 < 5; ++s5) {
                const float* wk = wc + (4 - s5) * 25 + ky * 5;
#pragma unroll
                for (int kx = 0; kx < 5; ++kx) {
                    float wv = wk[kx];
                    acc[s5][0] = fmaf(wv, rr[kx + 0], acc[s5][0]);
                    acc[s5][1] = fmaf(wv, rr[kx + 1], acc[s5][1]);
                    acc[s5][2] = fmaf(wv, rr[kx + 2], acc[s5][2]);
                    acc[s5][3] = fmaf(wv, rr[kx + 3], acc[s5][3]);
                }
            }
        }
        if (more) {
#pragma unroll
            for (int k = 0; k < 6; ++k) if (lofs[k] >= 0) buf[ibuf ^ 1][lofs[k]] = v[k];
        }
        int p = zp - 2;
        if (p >= zlo && p < zhi) {
            float* orow = o + p * SSZ + (y0 + ty) * S + tx * 4;
#pragma unroll
            for (int j = 0; j < 4; ++j) orow[j] = acc[0][j] + bv;
        }
#pragma unroll
        for (int s5 = 0; s5 < 4; ++s5)
#pragma unroll
            for (int j = 0; j < 4; ++j) acc[s5][j] = acc[s5 + 1][j];
#pragma unroll
        for (int j = 0; j < 4; ++j) acc[4][j] = 0.f;
        __syncthreads();
        ibuf ^= 1;
    }
#pragma unroll
    for (int s5 = 0; s5 < 4; ++s5) {
        int p = zp1 - 1 + s5;
        if (p >= zlo && p < zhi) {
            float* orow = o + p * SSZ + (y0 + ty) * S + tx * 4;
#pragma unroll
            for (int j = 0; j < 4; ++j) orow[j] = acc[s5][j] + bv;
        }
    }
}

// ---------------------------------------------------------------------------
// Kernel 2 (v5): depthwise 7x7x7 conv, dilation 3, pad 9, + bias -> att2
//
// = round-2 geometry EXACTLY (256 thr, 18 xcol x 14 rows, 5 ytiles,
//   RS7=108/RXS7=36, 4 outputs/thread, global_load_lds staging, ring acc)
// + ONE change: weights come from LDS via uniform-address ds_read_b128
//   broadcasts (layout [ky][kz][8], staged once per block). This removes
//   the per-iteration SMEM weight reloads (wv[343] remat) that shared
//   lgkmcnt with ds_reads and serialized the loop. No big local arrays:
//   only 2 float4 of weights live per (ky,s) step -> no spill.
// ---------------------------------------------------------------------------
#define RS7   108          // LDS row stride (dwords) = 3*36
#define RXS7  36           // rx substride (dwords), 30 used + 6 pad
#define NROW7 32           // rows gy = y0-9 .. y0+22   (14 out rows + 18 halo)
#define NCH7  14           // staging chunks of 256 dwords
#define LPP7  (NCH7*256)   // 3584 >= 32*108 = 3456

__global__ __launch_bounds__(256, 1) void conv7_dil(const float* __restrict__ in,
                                                    const float* __restrict__ w,   // [64][7][7][7]
                                                    const float* __restrict__ bias,
                                                    float* __restrict__ out) {
    const int ytile = blockIdx.x;        // 0..4  (14-row tiles, rows 56..69 partly masked)
    const int rz    = blockIdx.y;        // 0..2  (input z residue)
    const int bc    = blockIdx.z;        // 0..127
    const int c     = bc & (CH - 1);
    const int tid   = threadIdx.x;
    const int t18   = tid % 18;
    const int ty    = tid / 18;          // 0..14 (tid 252..255 inactive)
    const int tyc   = ty > 13 ? 13 : ty; // clamped for address safety
    const bool act  = (tid < 252);
    const int rx    = t18 % 3;
    const int ig    = t18 / 3;           // 0..5
    const int y0    = ytile * 14;

    const float* __restrict__ xin = in + (size_t)bc * SV;
    float* __restrict__ o         = out + (size_t)bc * SV;
    const float* __restrict__ wc  = w + c * 343;
    const float bv = bias[c];

    __shared__ __align__(16) float buf[2][LPP7];   // 28672 B
    __shared__ __align__(16) float wlds[7 * 56];   // [ky][kz][8] = 392 dw

    // ---- weights -> LDS, transposed to [ky][kz][kx] with kz-stride 8 ----
    for (int idx = tid; idx < 343; idx += 256) {
        int kz  = idx / 49;
        int rem = idx - kz * 49;
        int ky  = rem / 7;
        int kx  = rem - ky * 7;
        wlds[ky * 56 + kz * 8 + kx] = wc[idx];
    }

    // ---- staging offsets: linear LDS idx -> (r, rxs, ts) -> global byte ofs ----
    int gofs[NCH7];
#pragma unroll
    for (int k = 0; k < NCH7; ++k) {
        int idx = tid + (k << 8);
        int r   = idx / RS7;
        int rem = idx - r * RS7;
        int rxs = rem / RXS7;
        int ts  = rem - rxs * RXS7;
        int gy  = y0 - 9 + r;
        int gx  = 3 * ts + rxs - 9;
        gofs[k] = (r < NROW7 && ts < 30 && gy >= 0 && gy < S && gx >= 0 && gx < S)
                  ? (gy * S + gx) * 4 : -1;
    }

    const int zi0     = rz;
    const int zi_last = (S - 1) - ((S - 1 - rz) % 3);

    // ring accumulators: slot s holds output p = zi - 9 + 3s (weight kz = 6-s)
    float acc[7][4];
#pragma unroll
    for (int s = 0; s < 7; ++s)
#pragma unroll
        for (int j = 0; j < 4; ++j) acc[s][j] = 0.f;

    // prologue: stage plane zi0 into buf[0] (barrier below also covers wlds)
    {
        const char* pb = (const char*)(xin + (size_t)zi0 * SSZ);
#pragma unroll
        for (int k = 0; k < NCH7; ++k) {
            const float* gp = (gofs[k] >= 0) ? (const float*)(pb + gofs[k]) : &g_zero;
            __builtin_amdgcn_global_load_lds(
                (const __attribute__((address_space(1))) void*)gp,
                (__attribute__((address_space(3))) void*)&buf[0][tid + (k << 8)],
                4, 0, 0);
        }
    }
    __syncthreads();

    const int rbase = rx * RXS7 + 4 * ig;
    int ib = 0;
#pragma unroll 1
    for (int zi = zi0; zi <= zi_last; zi += 3) {
        // issue DMA for next plane into buf[ib^1]; drained at the barrier below
        if (zi < zi_last) {
            const char* pb = (const char*)(xin + (size_t)(zi + 3) * SSZ);
#pragma unroll
            for (int k = 0; k < NCH7; ++k) {
                const float* gp = (gofs[k] >= 0) ? (const float*)(pb + gofs[k]) : &g_zero;
                __builtin_amdgcn_global_load_lds(
                    (const __attribute__((address_space(1))) void*)gp,
                    (__attribute__((address_space(3))) void*)&buf[ib ^ 1][tid + (k << 8)],
                    4, 0, 0);
            }
        }

        const float* __restrict__ cur = buf[ib];
#pragma unroll
        for (int ky = 0; ky < 7; ++ky) {
            const float* rp = cur + (tyc + 3 * ky) * RS7 + rbase;
            float4 A  = *(const float4*)rp;          // t = 4ig .. 4ig+3
            float4 B  = *(const float4*)(rp + 4);    // t = 4ig+4 .. 4ig+7
            float2 Cc = *(const float2*)(rp + 8);    // t = 4ig+8, 4ig+9
            float rr[10] = {A.x, A.y, A.z, A.w, B.x, B.y, B.z, B.w, Cc.x, Cc.y};
#pragma unroll
            for (int s = 0; s < 7; ++s) {
                // uniform-address broadcast: 7 weights of (kz = 6-s, row ky)
                const float4* wq = (const float4*)&wlds[ky * 56 + (6 - s) * 8];
                const float4 qa = wq[0], qb = wq[1];
                const float wf0 = qa.x, wf1 = qa.y, wf2 = qa.z, wf3 = qa.w;
                const float wf4 = qb.x, wf5 = qb.y, wf6 = qb.z;
#pragma unroll
                for (int j = 0; j < 4; ++j) {
                    float a = acc[s][j];
                    a = fmaf(wf0, rr[0 + j], a);
                    a = fmaf(wf1, rr[1 + j], a);
                    a = fmaf(wf2, rr[2 + j], a);
                    a = fmaf(wf3, rr[3 + j], a);
                    a = fmaf(wf4, rr[4 + j], a);
                    a = fmaf(wf5, rr[5 + j], a);
                    a = fmaf(wf6, rr[6 + j], a);
                    acc[s][j] = a;
                }
            }
        }

        // emit slot 0: output plane p = zi - 9
        const int p  = zi - 9;
        const int yy = y0 + ty;
        if (p >= 0 && act && yy < S) {
            float* ob = o + p * SSZ + yy * S;
#pragma unroll
            for (int j = 0; j < 4; ++j) {
                const int xx = rx + 12 * ig + 3 * j;
                if (xx < S) ob[xx] = acc[0][j] + bv;
            }
        }
        // shift ring
#pragma unroll
        for (int s = 0; s < 6; ++s)
#pragma unroll
            for (int j = 0; j < 4; ++j) acc[s][j] = acc[s + 1][j];
#pragma unroll
        for (int j = 0; j < 4; ++j) acc[6][j] = 0.f;

        __syncthreads();   // drains DMA: buf[ib^1] complete for next iter
        ib ^= 1;
    }

    // flush: slot s holds p = zi_last - 6 + 3s  (s = 0..5)
    const int yy = y0 + ty;
#pragma unroll
    for (int s = 0; s < 6; ++s) {
        const int p = zi_last - 6 + 3 * s;
        if (p < S && act && yy < S) {
            float* ob = o + p * SSZ + yy * S;
#pragma unroll
            for (int j = 0; j < 4; ++j) {
                const int xx = rx + 12 * ig + 3 * j;
                if (xx < S) ob[xx] = acc[s][j] + bv;
            }
        }
    }
}

// ---------------------------------------------------------------------------
// Kernel 3: channel mean & max over the 128 channels of [att1; att2]
// ---------------------------------------------------------------------------
__global__ __launch_bounds__(256) void reduce_ch(const float* __restrict__ att1,
                                                 const float* __restrict__ att2,
                                                 float* __restrict__ pooled) {
    const int idx = blockIdx.x * 256 + threadIdx.x;    // over NB*SV/4
    const int e   = idx * 4;
    const int b   = e >> 18;                           // SV = 2^18
    const int s   = e & (SV - 1);
    const float4* a1 = (const float4*)(att1 + (size_t)b * CH * SV + s);
    const float4* a2 = (const float4*)(att2 + (size_t)b * CH * SV + s);
    const int stride = SV / 4;

    float4 sum = make_float4(0.f, 0.f, 0.f, 0.f);
    float4 mx  = make_float4(-3.4e38f, -3.4e38f, -3.4e38f, -3.4e38f);
#pragma unroll 8
    for (int c = 0; c < CH; ++c) {
        float4 v1 = a1[c * stride];
        float4 v2 = a2[c * stride];
        sum.x += v1.x + v2.x; sum.y += v1.y + v2.y;
        sum.z += v1.z + v2.z; sum.w += v1.w + v2.w;
        mx.x = fmaxf(mx.x, fmaxf(v1.x, v2.x)); mx.y = fmaxf(mx.y, fmaxf(v1.y, v2.y));
        mx.z = fmaxf(mx.z, fmaxf(v1.z, v2.z)); mx.w = fmaxf(mx.w, fmaxf(v1.w, v2.w));
    }
    const float inv = 1.f / 128.f;
    sum.x *= inv; sum.y *= inv; sum.z *= inv; sum.w *= inv;
    *(float4*)(pooled + (size_t)b * 2 * SV + s)      = sum;
    *(float4*)(pooled + (size_t)b * 2 * SV + SV + s) = mx;
}

// ---------------------------------------------------------------------------
// Kernel 4: gate = sigmoid(conv3d(pooled, ws, pad 3) + bs)   [B][2][64^3]
// ---------------------------------------------------------------------------
__global__ __launch_bounds__(256) void gate_conv(const float* __restrict__ pooled,
                                                 const float* __restrict__ wsg,  // [2][2][7][7][7]
                                                 const float* __restrict__ bs,
                                                 float* __restrict__ gate) {
    const int zc  = blockIdx.x;             // 0..63
    const int yt  = blockIdx.y;             // 0..7
    const int b   = blockIdx.z;             // 0..1
    const int tid = threadIdx.x;
    const int tx  = tid & 15;
    const int ty  = (tid >> 4) & 7;
    const int oc  = tid >> 7;
    const int y0  = yt * 8;

    __shared__ float sm[2][7][14][72];

    const float* __restrict__ pb = pooled + (size_t)b * 2 * SV;
    for (int idx = tid; idx < 2 * 7 * 14 * 70; idx += 256) {
        int ic   = idx / (7 * 14 * 70);
        int rem  = idx - ic * (7 * 14 * 70);
        int kz   = rem / (14 * 70);
        int rem2 = rem - kz * (14 * 70);
        int r    = rem2 / 70;
        int col  = rem2 - r * 70;
        int gz = zc + kz - 3, gy = y0 + r - 3, gx = col - 3;
        float v = 0.f;
        if (gz >= 0 && gz < S && gy >= 0 && gy < S && gx >= 0 && gx < S)
            v = pb[ic * SV + gz * SSZ + gy * S + gx];
        sm[ic][kz][r][col] = v;
    }
    __syncthreads();

    float acc[4] = {0.f, 0.f, 0.f, 0.f};
    const float* __restrict__ wo = wsg + oc * 686;
    for (int ic = 0; ic < 2; ++ic)
        for (int kz = 0; kz < 7; ++kz) {
#pragma unroll
            for (int ky = 0; ky < 7; ++ky) {
                const float* row = &sm[ic][kz][ty + ky][tx * 4];
                float rr[10];
#pragma unroll
                for (int q = 0; q < 10; ++q) rr[q] = row[q];
                const float* wr = wo + ic * 343 + kz * 49 + ky * 7;
#pragma unroll
                for (int kx = 0; kx < 7; ++kx) {
                    float wvv = wr[kx];
                    acc[0] = fmaf(wvv, rr[kx + 0], acc[0]);
                    acc[1] = fmaf(wvv, rr[kx + 1], acc[1]);
                    acc[2] = fmaf(wvv, rr[kx + 2], acc[2]);
                    acc[3] = fmaf(wvv, rr[kx + 3], acc[3]);
                }
            }
        }
    const float bvv = bs[oc];
    float* g = gate + ((size_t)b * 2 + oc) * SV + zc * SSZ + (y0 + ty) * S + tx * 4;
#pragma unroll
    for (int j = 0; j < 4; ++j)
        g[j] = 1.f / (1.f + __expf(-(acc[j] + bvv)));
}

// ---------------------------------------------------------------------------
// Kernel 5: out = att1*gate0 + att2*gate1 + x
// ---------------------------------------------------------------------------
__global__ __launch_bounds__(256) void combine(const float* __restrict__ att1,
                                               const float* __restrict__ att2,
                                               const float* __restrict__ x,
                                               const float* __restrict__ gate,
                                               float* __restrict__ out) {
    const int idx = blockIdx.x * 256 + threadIdx.x;    // over NB*CH*SV/4
    const int e   = idx * 4;
    const int b   = e >> 24;                           // CH*SV = 2^24
    const int s   = e & (SV - 1);
    float4 a1 = *(const float4*)(att1 + e);
    float4 a2 = *(const float4*)(att2 + e);
    float4 xv = *(const float4*)(x + e);
    float4 g0 = *(const float4*)(gate + (size_t)b * 2 * SV + s);
    float4 g1 = *(const float4*)(gate + (size_t)b * 2 * SV + SV + s);
    float4 r;
    r.x = a1.x * g0.x + a2.x * g1.x + xv.x;
    r.y = a1.y * g0.y + a2.y * g1.y + xv.y;
    r.z = a1.z * g0.z + a2.z * g1.z + xv.z;
    r.w = a1.w * g0.w + a2.w * g1.w + xv.w;
    *(float4*)(out + e) = r;
}

// ---------------------------------------------------------------------------
extern "C" void kernel_launch(void* const* d_in, const int* in_sizes, int n_in,
                              void* d_out, int out_size, void* d_ws, size_t ws_size,
                              hipStream_t stream) {
    const float* x   = (const float*)d_in[0];
    const float* w1  = (const float*)d_in[1];
    const float* b1  = (const float*)d_in[2];
    const float* w2  = (const float*)d_in[3];
    const float* b2  = (const float*)d_in[4];
    const float* wsg = (const float*)d_in[5];
    const float* bs  = (const float*)d_in[6];
    float* out = (float*)d_out;

    float* att1   = (float*)d_ws;                         // 2*64*SV floats
    float* att2   = att1 + (size_t)NB * CH * SV;          // 2*64*SV floats
    float* pooled = att2 + (size_t)NB * CH * SV;          // 2*2*SV floats
    float* gate   = pooled + (size_t)NB * 2 * SV;         // 2*2*SV floats

    conv5_dw <<<dim3(4, 2, NB * CH), 256, 0, stream>>>(x, w1, b1, att1);
    conv7_dil<<<dim3(5, 3, NB * CH), 256, 0, stream>>>(att1, w2, b2, att2);
    reduce_ch<<<(NB * SV / 4) / 256, 256, 0, stream>>>(att1, att2, pooled);
    gate_conv<<<dim3(S, 8, NB), 256, 0, stream>>>(pooled, wsg, bs, gate);
    combine  <<<(NB * CH * SV / 4) / 256, 256, 0, stream>>>(att1, att2, x, gate, out);
}